// Round 1
// baseline (617.646 us; speedup 1.0000x reference)
//
#include <hip/hip_runtime.h>
#include <hip/hip_bf16.h>
#include <stdint.h>

#define TT 1024
#define BB 32
#define DD 1024
#define MROWS (TT*BB)   // 32768
#define NCOLS (2*DD)    // 2048
#define KDIM  (DD)      // 1024
#define BK 32

typedef __attribute__((ext_vector_type(8))) short short8;
typedef __attribute__((ext_vector_type(4))) float f32x4;

__device__ __forceinline__ float bf2f(uint16_t u){
  union { uint32_t u; float f; } c; c.u = ((uint32_t)u) << 16; return c.f;
}
__device__ __forceinline__ uint16_t f2bf(float f){
  union { float f; uint32_t u; } c; c.f = f;
  uint32_t u = c.u;
  u += 0x7FFFu + ((u >> 16) & 1u);   // RNE
  return (uint16_t)(u >> 16);
}

// ---------------- convert x to bf16 ----------------
__global__ __launch_bounds__(256) void cvt_x_kernel(const float* __restrict__ x,
                                                    uint16_t* __restrict__ xb, int n4){
  int i = blockIdx.x * 256 + threadIdx.x;
  int stride = gridDim.x * 256;
  for (; i < n4; i += stride){
    float4 f = ((const float4*)x)[i];
    ushort4 o;
    o.x = f2bf(f.x); o.y = f2bf(f.y); o.z = f2bf(f.z); o.w = f2bf(f.w);
    ((ushort4*)xb)[i] = o;
  }
}

// ---------------- pack W_alpha|W_x to bf16 [2048][1024] ----------------
__global__ __launch_bounds__(256) void cvt_w_kernel(const float* __restrict__ Wa,
                                                    const float* __restrict__ Wx,
                                                    uint16_t* __restrict__ wc){
  const int half4 = DD*DD/4;  // 262144 float4s per matrix
  int i = blockIdx.x * 256 + threadIdx.x;  // 0..524287
  float4 f = (i < half4) ? ((const float4*)Wa)[i] : ((const float4*)Wx)[i - half4];
  ushort4 o;
  o.x = f2bf(f.x); o.y = f2bf(f.y); o.z = f2bf(f.z); o.w = f2bf(f.w);
  ((ushort4*)wc)[i] = o;
}

// ---------------- dual GEMM: C[m][e] = sum_d x[m][d]*Wc[e][d], e<1024 -> ax, else tanh(+bv) -> v
__global__ __launch_bounds__(256) void gemm_dual(const uint16_t* __restrict__ xb,
                                                 const uint16_t* __restrict__ wc,
                                                 const float* __restrict__ bv,
                                                 uint16_t* __restrict__ axo,
                                                 uint16_t* __restrict__ vo){
  __shared__ __align__(16) uint16_t As[128*BK];   // [row][k] 8KB
  __shared__ __align__(16) uint16_t Bs[128*BK];   // [col][k] 8KB
  const int tid  = threadIdx.x;
  const int lane = tid & 63;
  const int w    = tid >> 6;          // wave 0..3
  const int wm   = w >> 1, wn = w & 1; // 2x2 waves of 64x64
  const int bm   = blockIdx.y * 128;
  const int bn   = blockIdx.x * 128;

  f32x4 acc[4][4] = {};

  const int lrow = lane >> 2;         // 0..15
  const int lcol = (lane & 3) * 8;    // 0,8,16,24
  const int fr   = lane & 15;
  const int fk   = (lane >> 4) * 8;

  for (int k0 = 0; k0 < KDIM; k0 += BK){
    // stage: wave w covers rows w*32..w*32+31 of both tiles (2 chunks of 16 rows)
    #pragma unroll
    for (int c = 0; c < 2; ++c){
      const int rA = w*32 + c*16;
      const uint16_t* gA = xb + (size_t)(bm + rA + lrow)*KDIM + k0 + lcol;
      __builtin_amdgcn_global_load_lds((__attribute__((address_space(1))) const void*)gA,
                                       (__attribute__((address_space(3))) void*)(&As[rA*BK]),
                                       16, 0, 0);
      const uint16_t* gB = wc + (size_t)(bn + rA + lrow)*KDIM + k0 + lcol;
      __builtin_amdgcn_global_load_lds((__attribute__((address_space(1))) const void*)gB,
                                       (__attribute__((address_space(3))) void*)(&Bs[rA*BK]),
                                       16, 0, 0);
    }
    __syncthreads();   // drains vmcnt -> LDS tiles ready

    short8 aF[4], bF[4];
    #pragma unroll
    for (int m = 0; m < 4; ++m)
      aF[m] = *(const short8*)&As[(wm*64 + m*16 + fr)*BK + fk];
    #pragma unroll
    for (int n = 0; n < 4; ++n)
      bF[n] = *(const short8*)&Bs[(wn*64 + n*16 + fr)*BK + fk];

    #pragma unroll
    for (int m = 0; m < 4; ++m)
      #pragma unroll
      for (int n = 0; n < 4; ++n)
        acc[m][n] = __builtin_amdgcn_mfma_f32_16x16x32_bf16(aF[m], bF[n], acc[m][n], 0, 0, 0);

    __syncthreads();   // all waves done reading before next stage
  }

  // epilogue: C/D layout col=lane&15, row=(lane>>4)*4+reg
  const int fq = lane >> 4;
  const bool isV = (bn >= DD);
  #pragma unroll
  for (int m = 0; m < 4; ++m){
    #pragma unroll
    for (int n = 0; n < 4; ++n){
      #pragma unroll
      for (int j = 0; j < 4; ++j){
        const int row = bm + wm*64 + m*16 + fq*4 + j;
        const int col = bn + wn*64 + n*16 + fr;
        const float val = acc[m][n][j];
        if (!isV){
          axo[(size_t)row*DD + col] = f2bf(val);
        } else {
          const int e = col - DD;
          const float t = tanhf(val + bv[e]);
          vo[(size_t)row*DD + e] = f2bf(t);
        }
      }
    }
  }
}

// ---------------- scan over t: one thread per (b,e) ----------------
__global__ __launch_bounds__(128) void scan_kernel(const uint16_t* __restrict__ ax,
                                                   const uint16_t* __restrict__ vv,
                                                   const float* __restrict__ h0,
                                                   const float* __restrict__ d_alpha,
                                                   const float* __restrict__ b_alpha,
                                                   float* __restrict__ outs,
                                                   float* __restrict__ houts){
  const int idx = blockIdx.x * 128 + threadIdx.x;   // 0..32767 = b*D+e
  const int S = BB*DD;                              // 32768
  const int e = idx & (DD-1);
  const float da = d_alpha[e];
  const float ba = b_alpha[e];
  float h = h0[idx];
  houts[idx] = h;   // h[0] = h0

  float ar[4], vr[4];
  #pragma unroll
  for (int j = 0; j < 4; ++j){
    ar[j] = bf2f(ax[(size_t)j*S + idx]);
    vr[j] = bf2f(vv[(size_t)j*S + idx]);
  }

  for (int t = 0; t < TT; t += 4){
    float an[4] = {0.f,0.f,0.f,0.f}, vn[4] = {0.f,0.f,0.f,0.f};
    if (t + 4 < TT){
      #pragma unroll
      for (int j = 0; j < 4; ++j){
        an[j] = bf2f(ax[(size_t)(t+4+j)*S + idx]);
        vn[j] = bf2f(vv[(size_t)(t+4+j)*S + idx]);
      }
    }
    #pragma unroll
    for (int j = 0; j < 4; ++j){
      const float pre   = ar[j] + da*h + ba;
      const float alpha = 1.f/(1.f + __expf(-pre));
      h = alpha*(h - vr[j]) + vr[j];           // == alpha*h + (1-alpha)*v
      const float sg = 1.f/(1.f + __expf(-h));
      outs[(size_t)(t+j)*S + idx]    = h*h*sg; // h * silu(h)
      houts[(size_t)(t+j+1)*S + idx] = h;
    }
    #pragma unroll
    for (int j = 0; j < 4; ++j){ ar[j] = an[j]; vr[j] = vn[j]; }
  }
}

extern "C" void kernel_launch(void* const* d_in, const int* in_sizes, int n_in,
                              void* d_out, int out_size, void* d_ws, size_t ws_size,
                              hipStream_t stream){
  const float* x  = (const float*)d_in[0];
  const float* h0 = (const float*)d_in[1];
  const float* Wa = (const float*)d_in[2];
  const float* da = (const float*)d_in[3];
  const float* ba = (const float*)d_in[4];
  const float* Wx = (const float*)d_in[5];
  const float* bv = (const float*)d_in[6];

  float* outs  = (float*)d_out;                       // [T,B,D]
  float* houts = outs + (size_t)TT*BB*DD;             // [T+1,B,D]

  // workspace layout (bytes): wc 4MB | xb 64MB | ax 64MB | v 64MB  (~196MB)
  uint8_t* ws = (uint8_t*)d_ws;
  uint16_t* wc  = (uint16_t*)ws;
  uint16_t* xb  = (uint16_t*)(ws + (size_t)NCOLS*KDIM*2);
  uint16_t* axo = (uint16_t*)(ws + (size_t)NCOLS*KDIM*2 + (size_t)MROWS*KDIM*2);
  uint16_t* vo  = axo + (size_t)MROWS*DD;

  hipLaunchKernelGGL(cvt_w_kernel, dim3(2048), dim3(256), 0, stream, Wa, Wx, wc);
  hipLaunchKernelGGL(cvt_x_kernel, dim3(2048), dim3(256), 0, stream, x, xb, MROWS*KDIM/4);
  hipLaunchKernelGGL(gemm_dual, dim3(NCOLS/128, MROWS/128), dim3(256), 0, stream,
                     xb, wc, bv, axo, vo);
  hipLaunchKernelGGL(scan_kernel, dim3(MROWS/128 /*256 blocks*/), dim3(128), 0, stream,
                     axo, vo, h0, da, ba, outs, houts);
}

// Round 2
// 385.339 us; speedup vs baseline: 1.6029x; 1.6029x over previous
//
#include <hip/hip_runtime.h>
#include <hip/hip_bf16.h>
#include <stdint.h>

#define TT 1024
#define BB 32
#define DD 1024
#define MROWS (TT*BB)   // 32768
#define NCOLS (2*DD)    // 2048
#define KDIM  (DD)      // 1024
#define BK 64
#define SS (BB*DD)      // 32768

typedef __attribute__((ext_vector_type(8))) short short8;
typedef __attribute__((ext_vector_type(4))) float f32x4;

__device__ __forceinline__ float bf2f(uint16_t u){
  union { uint32_t u; float f; } c; c.u = ((uint32_t)u) << 16; return c.f;
}
__device__ __forceinline__ uint16_t f2bf(float f){
  union { float f; uint32_t u; } c; c.f = f;
  uint32_t u = c.u;
  u += 0x7FFFu + ((u >> 16) & 1u);   // RNE
  return (uint16_t)(u >> 16);
}
__device__ __forceinline__ float tanh_fast(float x){
  // 1 - 2/(1+e^{2x}): exact limits at +-inf, ~1e-7 rel error via v_exp_f32
  return 1.f - 2.f/(1.f + __expf(2.f*x));
}

// ---------------- convert x to bf16 ----------------
__global__ __launch_bounds__(256) void cvt_x_kernel(const float* __restrict__ x,
                                                    uint16_t* __restrict__ xb, int n4){
  int i = blockIdx.x * 256 + threadIdx.x;
  int stride = gridDim.x * 256;
  for (; i < n4; i += stride){
    float4 f = ((const float4*)x)[i];
    ushort4 o;
    o.x = f2bf(f.x); o.y = f2bf(f.y); o.z = f2bf(f.z); o.w = f2bf(f.w);
    ((ushort4*)xb)[i] = o;
  }
}

// ---------------- pack W_alpha|W_x to bf16 [2048][1024] ----------------
__global__ __launch_bounds__(256) void cvt_w_kernel(const float* __restrict__ Wa,
                                                    const float* __restrict__ Wx,
                                                    uint16_t* __restrict__ wc){
  const int half4 = DD*DD/4;
  int i = blockIdx.x * 256 + threadIdx.x;
  float4 f = (i < half4) ? ((const float4*)Wa)[i] : ((const float4*)Wx)[i - half4];
  ushort4 o;
  o.x = f2bf(f.x); o.y = f2bf(f.y); o.z = f2bf(f.z); o.w = f2bf(f.w);
  ((ushort4*)wc)[i] = o;
}

// ---------------- dual GEMM: C[m][e] = sum_d x[m][d]*Wc[e][d]
// e<1024 -> a-half of av; e>=1024 -> tanh(.+bv) -> v-half of av
// av layout: u32 at [t][b*D+e], low16 = a (bf16), high16 = v (bf16)
__global__ __launch_bounds__(256) void gemm_dual(const uint16_t* __restrict__ xb,
                                                 const uint16_t* __restrict__ wc,
                                                 const float* __restrict__ bv,
                                                 uint32_t* __restrict__ av){
  __shared__ __align__(16) uint16_t As[128*BK];   // 16KB, [row][64] bf16, slot-swizzled
  __shared__ __align__(16) uint16_t Bs[128*BK];   // 16KB
  const int tid  = threadIdx.x;
  const int lane = tid & 63;
  const int w    = tid >> 6;           // wave 0..3
  const int wm   = w >> 1, wn = w & 1; // 2x2 waves of 64x64

  // XCD-aware bijective swizzle (4096 % 8 == 0)
  const int bid  = blockIdx.x;                 // 0..4095
  const int bsw  = (bid & 7) * 512 + (bid >> 3);
  const int bn   = (bsw & 15) << 7;            // 0..2047 step 128
  const int bm   = (bsw >> 4) << 7;            // 0..32767 step 128

  f32x4 acc[4][4] = {};

  // staging: lane covers row (l>>3), 16B slot (l&7); source slot pre-swizzled
  const int sr = lane >> 3;            // 0..7 row within 8-row group
  const int srcoff = ((lane & 7) ^ sr) * 8;  // element offset within 64-elem row

  // ds_read byte addresses (swizzle applied), constant across K-loop
  const int fr = lane & 15;            // fragment row/col
  const int fq = lane >> 4;            // 0..3 -> k sub-slot
  int aaddr[2][4], baddr[2][4];
  #pragma unroll
  for (int kh = 0; kh < 2; ++kh){
    #pragma unroll
    for (int m = 0; m < 4; ++m){
      int ra = wm*64 + m*16 + fr;
      int pa = ((kh << 2) | fq) ^ (ra & 7);
      aaddr[kh][m] = ra*(BK*2) + pa*16;
      int rb = wn*64 + m*16 + fr;
      int pb = ((kh << 2) | fq) ^ (rb & 7);
      baddr[kh][m] = rb*(BK*2) + pb*16;
    }
  }

  for (int k0 = 0; k0 < KDIM; k0 += BK){
    #pragma unroll
    for (int c = 0; c < 4; ++c){
      const int rbase = w*32 + c*8;
      const uint16_t* gA = xb + (size_t)(bm + rbase + sr)*KDIM + k0 + srcoff;
      __builtin_amdgcn_global_load_lds((const __attribute__((address_space(1))) void*)gA,
                                       (__attribute__((address_space(3))) void*)(&As[rbase*BK]),
                                       16, 0, 0);
      const uint16_t* gB = wc + (size_t)(bn + rbase + sr)*KDIM + k0 + srcoff;
      __builtin_amdgcn_global_load_lds((const __attribute__((address_space(1))) void*)gB,
                                       (__attribute__((address_space(3))) void*)(&Bs[rbase*BK]),
                                       16, 0, 0);
    }
    __syncthreads();   // compiler drains vmcnt(0) -> tiles ready

    short8 aF[2][4], bF[2][4];
    #pragma unroll
    for (int kh = 0; kh < 2; ++kh){
      #pragma unroll
      for (int m = 0; m < 4; ++m){
        aF[kh][m] = *(const short8*)((const char*)As + aaddr[kh][m]);
        bF[kh][m] = *(const short8*)((const char*)Bs + baddr[kh][m]);
      }
    }
    #pragma unroll
    for (int kh = 0; kh < 2; ++kh)
      #pragma unroll
      for (int m = 0; m < 4; ++m)
        #pragma unroll
        for (int n = 0; n < 4; ++n)
          acc[m][n] = __builtin_amdgcn_mfma_f32_16x16x32_bf16(aF[kh][m], bF[kh][n], acc[m][n], 0, 0, 0);

    __syncthreads();
  }

  // epilogue: C/D layout col=lane&15, row=(lane>>4)*4+j
  const bool isV = (bn >= DD);
  uint16_t* av16 = (uint16_t*)av;
  #pragma unroll
  for (int n = 0; n < 4; ++n){
    const int col = bn + wn*64 + n*16 + fr;
    const int e   = isV ? (col - DD) : col;
    const float bvn = isV ? bv[e] : 0.f;
    #pragma unroll
    for (int m = 0; m < 4; ++m){
      #pragma unroll
      for (int j = 0; j < 4; ++j){
        const int row = bm + wm*64 + m*16 + fq*4 + j;
        float val = acc[m][n][j];
        if (isV) val = tanh_fast(val + bvn);
        const int t = row >> 5, b = row & 31;
        const size_t widx = (size_t)t*SS + b*DD + e;
        av16[widx*2 + (isV ? 1 : 0)] = f2bf(val);
      }
    }
  }
}

// ---------------- scan over t: one thread per (b,e), depth-32 prefetch ----------------
#define SCAN_STEP(u, tcur)                                        \
  {                                                               \
    const float a_ = bf2f((uint16_t)(u));                         \
    const float v_ = bf2f((uint16_t)((u) >> 16));                 \
    const float pre_ = a_ + da*h + ba;                            \
    const float al_ = 1.f/(1.f + __expf(-pre_));                  \
    h = al_*(h - v_) + v_;                                        \
    const float sg_ = 1.f/(1.f + __expf(-h));                     \
    outs[(size_t)(tcur)*SS + idx]     = h*h*sg_;                  \
    houts[(size_t)((tcur)+1)*SS + idx] = h;                       \
  }

__global__ __launch_bounds__(64) void scan_kernel(const uint32_t* __restrict__ av,
                                                  const float* __restrict__ h0,
                                                  const float* __restrict__ d_alpha,
                                                  const float* __restrict__ b_alpha,
                                                  float* __restrict__ outs,
                                                  float* __restrict__ houts){
  const int idx = blockIdx.x * 64 + threadIdx.x;   // 0..32767 = b*D+e
  const int e = idx & (DD-1);
  const float da = d_alpha[e];
  const float ba = b_alpha[e];
  float h = h0[idx];
  houts[idx] = h;

  uint32_t bufA[32], bufB[32];
  #pragma unroll
  for (int j = 0; j < 32; ++j) bufA[j] = av[(size_t)j*SS + idx];

  for (int t0 = 0; t0 < TT; t0 += 64){
    #pragma unroll
    for (int j = 0; j < 32; ++j) bufB[j] = av[(size_t)(t0+32+j)*SS + idx];
    #pragma unroll
    for (int j = 0; j < 32; ++j) SCAN_STEP(bufA[j], t0 + j);
    if (t0 + 64 < TT){
      #pragma unroll
      for (int j = 0; j < 32; ++j) bufA[j] = av[(size_t)(t0+64+j)*SS + idx];
    }
    #pragma unroll
    for (int j = 0; j < 32; ++j) SCAN_STEP(bufB[j], t0 + 32 + j);
  }
}

extern "C" void kernel_launch(void* const* d_in, const int* in_sizes, int n_in,
                              void* d_out, int out_size, void* d_ws, size_t ws_size,
                              hipStream_t stream){
  const float* x  = (const float*)d_in[0];
  const float* h0 = (const float*)d_in[1];
  const float* Wa = (const float*)d_in[2];
  const float* da = (const float*)d_in[3];
  const float* ba = (const float*)d_in[4];
  const float* Wx = (const float*)d_in[5];
  const float* bv = (const float*)d_in[6];

  float* outs  = (float*)d_out;                       // [T,B,D]
  float* houts = outs + (size_t)TT*BB*DD;             // [T+1,B,D]

  // workspace: wc 4MB | xb 64MB | av 128MB
  uint8_t* ws = (uint8_t*)d_ws;
  uint16_t* wcb = (uint16_t*)ws;
  uint16_t* xb  = (uint16_t*)(ws + (size_t)NCOLS*KDIM*2);
  uint32_t* av  = (uint32_t*)(ws + (size_t)NCOLS*KDIM*2 + (size_t)MROWS*KDIM*2);

  hipLaunchKernelGGL(cvt_w_kernel, dim3(2048), dim3(256), 0, stream, Wa, Wx, wcb);
  hipLaunchKernelGGL(cvt_x_kernel, dim3(2048), dim3(256), 0, stream, x, xb, MROWS*KDIM/4);
  hipLaunchKernelGGL(gemm_dual, dim3((NCOLS/128)*(MROWS/128)), dim3(256), 0, stream,
                     xb, wcb, bv, av);
  hipLaunchKernelGGL(scan_kernel, dim3(SS/64), dim3(64), 0, stream,
                     av, h0, da, ba, outs, houts);
}

// Round 3
// 294.745 us; speedup vs baseline: 2.0955x; 1.3074x over previous
//
#include <hip/hip_runtime.h>
#include <hip/hip_bf16.h>
#include <stdint.h>

#define TT 1024
#define BB 32
#define DD 1024
#define MROWS (TT*BB)   // 32768
#define NCOLS (2*DD)    // 2048
#define KDIM  (DD)      // 1024
#define BK 64
#define SS (BB*DD)      // 32768

typedef __attribute__((ext_vector_type(8))) short short8;
typedef __attribute__((ext_vector_type(4))) float f32x4;

__device__ __forceinline__ float bf2f(uint16_t u){
  union { uint32_t u; float f; } c; c.u = ((uint32_t)u) << 16; return c.f;
}
__device__ __forceinline__ uint16_t f2bf(float f){
  union { float f; uint32_t u; } c; c.f = f;
  uint32_t u = c.u;
  u += 0x7FFFu + ((u >> 16) & 1u);   // RNE
  return (uint16_t)(u >> 16);
}
__device__ __forceinline__ float tanh_fast(float x){
  return 1.f - 2.f/(1.f + __expf(2.f*x));
}
__device__ __forceinline__ float sigmoid_fast(float x){
  // 1/(1+exp(-x)) with v_rcp_f32 (approx, ~1ulp) instead of exact divide
  return __builtin_amdgcn_rcpf(1.f + __expf(-x));
}

// ---------------- convert x to bf16 ----------------
__global__ __launch_bounds__(256) void cvt_x_kernel(const float* __restrict__ x,
                                                    uint16_t* __restrict__ xb, int n4){
  int i = blockIdx.x * 256 + threadIdx.x;
  int stride = gridDim.x * 256;
  for (; i < n4; i += stride){
    float4 f = ((const float4*)x)[i];
    ushort4 o;
    o.x = f2bf(f.x); o.y = f2bf(f.y); o.z = f2bf(f.z); o.w = f2bf(f.w);
    ((ushort4*)xb)[i] = o;
  }
}

// ---------------- pack W to bf16, pair-interleaved ----------------
// wc row c (0..2047): e = ((c>>5)<<4) | (c&15), s = (c>>4)&1; wc[c] = (s?Wx:Wa)[e]
// -> within any aligned 32-row group, rows 0..15 are Wa[e0..e0+15], rows 16..31 are Wx[e0..e0+15]
__global__ __launch_bounds__(256) void cvt_w_kernel(const float* __restrict__ Wa,
                                                    const float* __restrict__ Wx,
                                                    uint16_t* __restrict__ wc){
  int i = blockIdx.x * 256 + threadIdx.x;   // 0..524287 float4 units
  const int c    = i >> 8;                  // 0..2047
  const int col4 = i & 255;
  const int e = ((c >> 5) << 4) | (c & 15);
  const int s = (c >> 4) & 1;
  const float* src = (s ? Wx : Wa) + (size_t)e*DD + col4*4;
  float4 f = *(const float4*)src;
  ushort4 o;
  o.x = f2bf(f.x); o.y = f2bf(f.y); o.z = f2bf(f.z); o.w = f2bf(f.w);
  ((ushort4*)wc)[i] = o;
}

// ---------------- dual GEMM: fragment n even -> a, n odd -> v (same e-range)
// av[t*SS + b*DD + e] : low16 = a (bf16), high16 = tanh(v+bv) (bf16)
__global__ __launch_bounds__(256) void gemm_dual(const uint16_t* __restrict__ xb,
                                                 const uint16_t* __restrict__ wc,
                                                 const float* __restrict__ bv,
                                                 uint32_t* __restrict__ av){
  __shared__ __align__(16) uint16_t As[128*BK];   // 16KB, swizzled
  __shared__ __align__(16) uint16_t Bs[128*BK];   // 16KB
  const int tid  = threadIdx.x;
  const int lane = tid & 63;
  const int w    = tid >> 6;           // wave 0..3
  const int wm   = w >> 1, wn = w & 1; // 2x2 waves of 64x64

  // XCD-aware bijective swizzle (4096 % 8 == 0)
  const int bid  = blockIdx.x;
  const int bsw  = (bid & 7) * 512 + (bid >> 3);
  const int bn   = (bsw & 15) << 7;            // col-tile 0..2047 step 128
  const int bm   = (bsw >> 4) << 7;            // row-tile 0..32767 step 128

  f32x4 acc[4][4] = {};

  const int sr = lane >> 3;                  // row 0..7 in 8-row staging group
  const int srcoff = ((lane & 7) ^ sr) * 8;  // pre-swizzled source slot

  const int fr = lane & 15;
  const int fq = lane >> 4;
  int aaddr[2][4], baddr[2][4];
  #pragma unroll
  for (int kh = 0; kh < 2; ++kh){
    #pragma unroll
    for (int m = 0; m < 4; ++m){
      int ra = wm*64 + m*16 + fr;
      int pa = ((kh << 2) | fq) ^ (ra & 7);
      aaddr[kh][m] = ra*(BK*2) + pa*16;
      int rb = wn*64 + m*16 + fr;
      int pb = ((kh << 2) | fq) ^ (rb & 7);
      baddr[kh][m] = rb*(BK*2) + pb*16;
    }
  }

  for (int k0 = 0; k0 < KDIM; k0 += BK){
    #pragma unroll
    for (int c = 0; c < 4; ++c){
      const int rbase = w*32 + c*8;
      const uint16_t* gA = xb + (size_t)(bm + rbase + sr)*KDIM + k0 + srcoff;
      __builtin_amdgcn_global_load_lds((const __attribute__((address_space(1))) void*)gA,
                                       (__attribute__((address_space(3))) void*)(&As[rbase*BK]),
                                       16, 0, 0);
      const uint16_t* gB = wc + (size_t)(bn + rbase + sr)*KDIM + k0 + srcoff;
      __builtin_amdgcn_global_load_lds((const __attribute__((address_space(1))) void*)gB,
                                       (__attribute__((address_space(3))) void*)(&Bs[rbase*BK]),
                                       16, 0, 0);
    }
    __syncthreads();

    short8 aF[2][4], bF[2][4];
    #pragma unroll
    for (int kh = 0; kh < 2; ++kh){
      #pragma unroll
      for (int m = 0; m < 4; ++m){
        aF[kh][m] = *(const short8*)((const char*)As + aaddr[kh][m]);
        bF[kh][m] = *(const short8*)((const char*)Bs + baddr[kh][m]);
      }
    }
    #pragma unroll
    for (int kh = 0; kh < 2; ++kh)
      #pragma unroll
      for (int m = 0; m < 4; ++m)
        #pragma unroll
        for (int n = 0; n < 4; ++n)
          acc[m][n] = __builtin_amdgcn_mfma_f32_16x16x32_bf16(aF[kh][m], bF[kh][n], acc[m][n], 0, 0, 0);

    __syncthreads();
  }

  // epilogue: C/D col=lane&15, row=(lane>>4)*4+j. Fragment pair (2p, 2p+1) = (a, v) for
  // e = ebase + p*16 + fr. One packed u32 store per element.
  const int ebase = (bn + wn*64) >> 1;
  #pragma unroll
  for (int p = 0; p < 2; ++p){
    const int e = ebase + p*16 + fr;
    const float bvn = bv[e];
    #pragma unroll
    for (int m = 0; m < 4; ++m){
      #pragma unroll
      for (int j = 0; j < 4; ++j){
        const int row = bm + wm*64 + m*16 + fq*4 + j;
        const float a  = acc[m][2*p][j];
        const float vt = tanh_fast(acc[m][2*p+1][j] + bvn);
        const int t = row >> 5, b = row & 31;
        av[(size_t)t*SS + (size_t)b*DD + e] = (uint32_t)f2bf(a) | ((uint32_t)f2bf(vt) << 16);
      }
    }
  }
}

// ---------------- scan over t: one thread per (b,e), depth-32 prefetch ----------------
#define SCAN_STEP(u, tcur)                                        \
  {                                                               \
    const float a_ = bf2f((uint16_t)(u));                         \
    const float v_ = bf2f((uint16_t)((u) >> 16));                 \
    const float al_ = sigmoid_fast(a_ + da*h + ba);               \
    h = al_*(h - v_) + v_;                                        \
    const float sg_ = sigmoid_fast(h);                            \
    __builtin_nontemporal_store(h*h*sg_, &outs[(size_t)(tcur)*SS + idx]); \
    __builtin_nontemporal_store(h, &houts[(size_t)((tcur)+1)*SS + idx]);  \
  }

__global__ __launch_bounds__(64) void scan_kernel(const uint32_t* __restrict__ av,
                                                  const float* __restrict__ h0,
                                                  const float* __restrict__ d_alpha,
                                                  const float* __restrict__ b_alpha,
                                                  float* __restrict__ outs,
                                                  float* __restrict__ houts){
  const int idx = blockIdx.x * 64 + threadIdx.x;   // 0..32767 = b*D+e
  const int e = idx & (DD-1);
  const float da = d_alpha[e];
  const float ba = b_alpha[e];
  float h = h0[idx];
  __builtin_nontemporal_store(h, &houts[idx]);

  uint32_t bufA[32], bufB[32];
  #pragma unroll
  for (int j = 0; j < 32; ++j) bufA[j] = av[(size_t)j*SS + idx];

  for (int t0 = 0; t0 < TT; t0 += 64){
    #pragma unroll
    for (int j = 0; j < 32; ++j) bufB[j] = av[(size_t)(t0+32+j)*SS + idx];
    #pragma unroll
    for (int j = 0; j < 32; ++j) SCAN_STEP(bufA[j], t0 + j);
    if (t0 + 64 < TT){
      #pragma unroll
      for (int j = 0; j < 32; ++j) bufA[j] = av[(size_t)(t0+64+j)*SS + idx];
    }
    #pragma unroll
    for (int j = 0; j < 32; ++j) SCAN_STEP(bufB[j], t0 + 32 + j);
  }
}

extern "C" void kernel_launch(void* const* d_in, const int* in_sizes, int n_in,
                              void* d_out, int out_size, void* d_ws, size_t ws_size,
                              hipStream_t stream){
  const float* x  = (const float*)d_in[0];
  const float* h0 = (const float*)d_in[1];
  const float* Wa = (const float*)d_in[2];
  const float* da = (const float*)d_in[3];
  const float* ba = (const float*)d_in[4];
  const float* Wx = (const float*)d_in[5];
  const float* bv = (const float*)d_in[6];

  float* outs  = (float*)d_out;                       // [T,B,D]
  float* houts = outs + (size_t)TT*BB*DD;             // [T+1,B,D]

  // workspace: wc 4MB | xb 64MB | av 128MB
  uint8_t* ws = (uint8_t*)d_ws;
  uint16_t* wcb = (uint16_t*)ws;
  uint16_t* xb  = (uint16_t*)(ws + (size_t)NCOLS*KDIM*2);
  uint32_t* av  = (uint32_t*)(ws + (size_t)NCOLS*KDIM*2 + (size_t)MROWS*KDIM*2);

  hipLaunchKernelGGL(cvt_w_kernel, dim3(2048), dim3(256), 0, stream, Wa, Wx, wcb);
  hipLaunchKernelGGL(cvt_x_kernel, dim3(2048), dim3(256), 0, stream, x, xb, MROWS*KDIM/4);
  hipLaunchKernelGGL(gemm_dual, dim3((NCOLS/128)*(MROWS/128)), dim3(256), 0, stream,
                     xb, wcb, bv, av);
  hipLaunchKernelGGL(scan_kernel, dim3(SS/64), dim3(64), 0, stream,
                     av, h0, da, ba, outs, houts);
}

// Round 4
// 273.192 us; speedup vs baseline: 2.2609x; 1.0789x over previous
//
#include <hip/hip_runtime.h>
#include <hip/hip_bf16.h>
#include <stdint.h>

#define TT 1024
#define BB 32
#define DD 1024
#define MROWS (TT*BB)   // 32768
#define NCOLS (2*DD)    // 2048
#define KDIM  (DD)      // 1024
#define SS (BB*DD)      // 32768

typedef __attribute__((ext_vector_type(8))) short short8;
typedef __attribute__((ext_vector_type(4))) float f32x4;

__device__ __forceinline__ float bf2f(uint16_t u){
  union { uint32_t u; float f; } c; c.u = ((uint32_t)u) << 16; return c.f;
}
__device__ __forceinline__ uint16_t f2bf(float f){
  union { float f; uint32_t u; } c; c.f = f;
  uint32_t u = c.u;
  u += 0x7FFFu + ((u >> 16) & 1u);   // RNE
  return (uint16_t)(u >> 16);
}
__device__ __forceinline__ float tanh_fast(float x){
  return 1.f - 2.f/(1.f + __expf(2.f*x));
}
__device__ __forceinline__ float sigmoid_fast(float x){
  return __builtin_amdgcn_rcpf(1.f + __expf(-x));
}

// ---------------- convert x to bf16 ----------------
__global__ __launch_bounds__(256) void cvt_x_kernel(const float* __restrict__ x,
                                                    uint16_t* __restrict__ xb, int n4){
  int i = blockIdx.x * 256 + threadIdx.x;
  int stride = gridDim.x * 256;
  for (; i < n4; i += stride){
    float4 f = ((const float4*)x)[i];
    ushort4 o;
    o.x = f2bf(f.x); o.y = f2bf(f.y); o.z = f2bf(f.z); o.w = f2bf(f.w);
    ((ushort4*)xb)[i] = o;
  }
}

// ---------------- pack W to bf16, pair-interleaved ----------------
// wc row c: e = ((c>>5)<<4)|(c&15), s=(c>>4)&1; wc[c] = (s?Wx:Wa)[e]
__global__ __launch_bounds__(256) void cvt_w_kernel(const float* __restrict__ Wa,
                                                    const float* __restrict__ Wx,
                                                    uint16_t* __restrict__ wc){
  int i = blockIdx.x * 256 + threadIdx.x;   // float4 units
  const int c    = i >> 8;
  const int col4 = i & 255;
  const int e = ((c >> 5) << 4) | (c & 15);
  const int s = (c >> 4) & 1;
  const float* src = (s ? Wx : Wa) + (size_t)e*DD + col4*4;
  float4 f = *(const float4*)src;
  ushort4 o;
  o.x = f2bf(f.x); o.y = f2bf(f.y); o.z = f2bf(f.z); o.w = f2bf(f.w);
  ((ushort4*)wc)[i] = o;
}

// ---------------- dual GEMM, 256x256 tile, 8-phase schedule ----------------
// C[m][c] = sum_d x[m][d]*wc[c][d]; col pairs (even n -> a, odd n -> v);
// av[t*SS+b*DD+e]: low16 = a, high16 = tanh(v + bv)
__global__ __launch_bounds__(512, 2) void gemm_dual(const uint16_t* __restrict__ xb,
                                                    const uint16_t* __restrict__ wc,
                                                    const float* __restrict__ bv,
                                                    uint32_t* __restrict__ av){
  // 128 KiB: A[2 buf][256 rows][64 k] @ byte 0; B[2][256][64] @ byte 65536
  __shared__ __align__(16) uint16_t lds[65536];
  char* ldsc = (char*)lds;

  const int tid  = threadIdx.x;        // 0..511
  const int lane = tid & 63;
  const int w    = tid >> 6;           // wave 0..7
  const int wm   = w >> 2;             // 0..1
  const int wn   = w & 3;              // 0..3
  const int fr   = lane & 15;
  const int fq   = lane >> 4;

  // XCD-aware bijective swizzle: 1024 blocks, 8 XCDs
  const int bid = blockIdx.x;
  const int bsw = (bid & 7) * 128 + (bid >> 3);
  const int bm  = (bsw >> 3) << 8;     // row-tile * 256 (0..127)
  const int bn  = (bsw & 7) << 8;      // col-tile * 256 (0..7)

  f32x4 acc[8][4] = {};

  // staging: thread -> row (tid>>3), 16B slot (tid&7); source pre-swizzled (rule #21)
  const int srow = tid >> 3;                     // 0..63
  const int soff = ((tid & 7) ^ (srow & 7)) * 8; // element offset within 64-elem row

  // stage unit q (0:A rows0-127, 1:A rows128-255, 2:B rows0-127, 3:B rows128-255)
  // of K-tile kt into LDS buffer kt&1. 2 x global_load_lds(16B) per thread.
  #define STAGE(kt, q) { \
    const uint16_t* src_ = ((q) < 2) ? xb : wc; \
    const int gbase_ = ((q) < 2) ? bm : bn; \
    const int region_ = ((q) < 2) ? 0 : 65536; \
    const int rb0_ = ((q) & 1) * 128; \
    const int k0_ = (kt) * 64; \
    _Pragma("unroll") \
    for (int c_ = 0; c_ < 2; ++c_){ \
      const uint16_t* g_ = src_ + (size_t)(gbase_ + rb0_ + c_*64 + srow)*KDIM + k0_ + soff; \
      char* d_ = ldsc + region_ + ((kt) & 1)*32768 + (rb0_ + c_*64 + w*8)*128; \
      __builtin_amdgcn_global_load_lds((const __attribute__((address_space(1))) void*)g_, \
                                       (__attribute__((address_space(3))) void*)d_, 16, 0, 0); \
    } \
  }

  // prologue: stage tile 0, drain, barrier
  STAGE(0,0) STAGE(0,1) STAGE(0,2) STAGE(0,3)
  asm volatile("s_waitcnt vmcnt(0)" ::: "memory");
  __builtin_amdgcn_s_barrier();

  for (int t = 0; t < 16; ++t){
    const int nbuf = (t & 1) * 32768;
    const int aB0 = nbuf + (wm*128 + fr)*128;
    const int bB0 = 65536 + nbuf + (wn*64 + fr)*128;
    int aK[2], bK[2];
    #pragma unroll
    for (int kh = 0; kh < 2; ++kh){
      const int ps = ((kh*4 + fq) ^ (fr & 7)) * 16;
      aK[kh] = aB0 + ps;
      bK[kh] = bB0 + ps;
    }

    // phase q: C-quadrant (rows (q&1)*64, cols (q>>1)*32 of the wave's 128x64), K=64
    #define PHASE(q) { \
      short8 aF[4][2], bF[2][2]; \
      _Pragma("unroll") \
      for (int m = 0; m < 4; ++m) \
        _Pragma("unroll") \
        for (int kh = 0; kh < 2; ++kh) \
          aF[m][kh] = *(const short8*)(ldsc + aK[kh] + (((q)&1)*8192 + m*2048)); \
      _Pragma("unroll") \
      for (int n = 0; n < 2; ++n) \
        _Pragma("unroll") \
        for (int kh = 0; kh < 2; ++kh) \
          bF[n][kh] = *(const short8*)(ldsc + bK[kh] + (((q)>>1)*4096 + n*2048)); \
      if (t < 15) STAGE(t+1, q) \
      __builtin_amdgcn_s_barrier(); \
      asm volatile("s_waitcnt lgkmcnt(0)" ::: "memory"); \
      __builtin_amdgcn_sched_barrier(0); \
      __builtin_amdgcn_s_setprio(1); \
      _Pragma("unroll") \
      for (int m = 0; m < 4; ++m) \
        _Pragma("unroll") \
        for (int n = 0; n < 2; ++n) \
          _Pragma("unroll") \
          for (int kh = 0; kh < 2; ++kh) \
            acc[((q)&1)*4+m][((q)>>1)*2+n] = \
              __builtin_amdgcn_mfma_f32_16x16x32_bf16(aF[m][kh], bF[n][kh], \
                                                      acc[((q)&1)*4+m][((q)>>1)*2+n], 0, 0, 0); \
      __builtin_amdgcn_s_setprio(0); \
      if ((q) == 3) asm volatile("s_waitcnt vmcnt(0)" ::: "memory"); \
      __builtin_amdgcn_s_barrier(); \
    }

    PHASE(0) PHASE(1) PHASE(2) PHASE(3)
    #undef PHASE
  }
  #undef STAGE

  // epilogue: C/D col=lane&15, row=(lane>>4)*4+j; frag pair (2p,2p+1) = (a,v)
  const int ebase = (bn + wn*64) >> 1;
  #pragma unroll
  for (int p = 0; p < 2; ++p){
    const int e = ebase + p*16 + fr;
    const float bvn = bv[e];
    #pragma unroll
    for (int m = 0; m < 8; ++m){
      #pragma unroll
      for (int j = 0; j < 4; ++j){
        const int row = bm + wm*128 + m*16 + fq*4 + j;
        const float a  = acc[m][2*p][j];
        const float vt = tanh_fast(acc[m][2*p+1][j] + bvn);
        const int tt = row >> 5, b = row & 31;
        av[(size_t)tt*SS + (size_t)b*DD + e] = (uint32_t)f2bf(a) | ((uint32_t)f2bf(vt) << 16);
      }
    }
  }
}

// ---------------- scan over t: one thread per (b,e), depth-32 prefetch ----------------
#define SCAN_STEP(u, tcur)                                        \
  {                                                               \
    const float a_ = bf2f((uint16_t)(u));                         \
    const float v_ = bf2f((uint16_t)((u) >> 16));                 \
    const float al_ = sigmoid_fast(a_ + da*h + ba);               \
    h = al_*(h - v_) + v_;                                        \
    const float sg_ = sigmoid_fast(h);                            \
    __builtin_nontemporal_store(h*h*sg_, &outs[(size_t)(tcur)*SS + idx]); \
    __builtin_nontemporal_store(h, &houts[(size_t)((tcur)+1)*SS + idx]);  \
  }

__global__ __launch_bounds__(64) void scan_kernel(const uint32_t* __restrict__ av,
                                                  const float* __restrict__ h0,
                                                  const float* __restrict__ d_alpha,
                                                  const float* __restrict__ b_alpha,
                                                  float* __restrict__ outs,
                                                  float* __restrict__ houts){
  const int idx = blockIdx.x * 64 + threadIdx.x;   // 0..32767 = b*D+e
  const int e = idx & (DD-1);
  const float da = d_alpha[e];
  const float ba = b_alpha[e];
  float h = h0[idx];
  __builtin_nontemporal_store(h, &houts[idx]);

  uint32_t bufA[32], bufB[32];
  #pragma unroll
  for (int j = 0; j < 32; ++j) bufA[j] = av[(size_t)j*SS + idx];

  for (int t0 = 0; t0 < TT; t0 += 64){
    #pragma unroll
    for (int j = 0; j < 32; ++j) bufB[j] = av[(size_t)(t0+32+j)*SS + idx];
    #pragma unroll
    for (int j = 0; j < 32; ++j) SCAN_STEP(bufA[j], t0 + j);
    if (t0 + 64 < TT){
      #pragma unroll
      for (int j = 0; j < 32; ++j) bufA[j] = av[(size_t)(t0+64+j)*SS + idx];
    }
    #pragma unroll
    for (int j = 0; j < 32; ++j) SCAN_STEP(bufB[j], t0 + 32 + j);
  }
}

extern "C" void kernel_launch(void* const* d_in, const int* in_sizes, int n_in,
                              void* d_out, int out_size, void* d_ws, size_t ws_size,
                              hipStream_t stream){
  const float* x  = (const float*)d_in[0];
  const float* h0 = (const float*)d_in[1];
  const float* Wa = (const float*)d_in[2];
  const float* da = (const float*)d_in[3];
  const float* ba = (const float*)d_in[4];
  const float* Wx = (const float*)d_in[5];
  const float* bv = (const float*)d_in[6];

  float* outs  = (float*)d_out;                       // [T,B,D]
  float* houts = outs + (size_t)TT*BB*DD;             // [T+1,B,D]

  // workspace: wc 4MB | xb 64MB | av 128MB
  uint8_t* ws = (uint8_t*)d_ws;
  uint16_t* wcb = (uint16_t*)ws;
  uint16_t* xb  = (uint16_t*)(ws + (size_t)NCOLS*KDIM*2);
  uint32_t* av  = (uint32_t*)(ws + (size_t)NCOLS*KDIM*2 + (size_t)MROWS*KDIM*2);

  hipLaunchKernelGGL(cvt_w_kernel, dim3(2048), dim3(256), 0, stream, Wa, Wx, wcb);
  hipLaunchKernelGGL(cvt_x_kernel, dim3(2048), dim3(256), 0, stream, x, xb, MROWS*KDIM/4);
  hipLaunchKernelGGL(gemm_dual, dim3((NCOLS/256)*(MROWS/256)), dim3(512), 0, stream,
                     xb, wcb, bv, av);
  hipLaunchKernelGGL(scan_kernel, dim3(SS/64), dim3(64), 0, stream,
                     av, h0, da, ba, outs, houts);
}

// Round 5
// 266.315 us; speedup vs baseline: 2.3192x; 1.0258x over previous
//
#include <hip/hip_runtime.h>
#include <hip/hip_bf16.h>
#include <stdint.h>

#define TT 1024
#define BB 32
#define DD 1024
#define MROWS (TT*BB)   // 32768
#define NCOLS (2*DD)    // 2048
#define KDIM  (DD)      // 1024
#define SS (BB*DD)      // 32768

typedef __attribute__((ext_vector_type(8))) short short8;
typedef __attribute__((ext_vector_type(4))) float f32x4;

__device__ __forceinline__ float bf2f(uint16_t u){
  union { uint32_t u; float f; } c; c.u = ((uint32_t)u) << 16; return c.f;
}
__device__ __forceinline__ uint16_t f2bf(float f){
  union { float f; uint32_t u; } c; c.f = f;
  uint32_t u = c.u;
  u += 0x7FFFu + ((u >> 16) & 1u);   // RNE
  return (uint16_t)(u >> 16);
}
__device__ __forceinline__ float tanh_fast(float x){
  return 1.f - 2.f/(1.f + __expf(2.f*x));
}
__device__ __forceinline__ float sigmoid_fast(float x){
  return __builtin_amdgcn_rcpf(1.f + __expf(-x));
}

// ---------------- convert x to bf16 ----------------
__global__ __launch_bounds__(256) void cvt_x_kernel(const float* __restrict__ x,
                                                    uint16_t* __restrict__ xb, int n4){
  int i = blockIdx.x * 256 + threadIdx.x;
  int stride = gridDim.x * 256;
  for (; i < n4; i += stride){
    float4 f = ((const float4*)x)[i];
    ushort4 o;
    o.x = f2bf(f.x); o.y = f2bf(f.y); o.z = f2bf(f.z); o.w = f2bf(f.w);
    ((ushort4*)xb)[i] = o;
  }
}

// ---------------- pack W to bf16, pair-interleaved ----------------
// wc row c: e = ((c>>5)<<4)|(c&15), s=(c>>4)&1; wc[c] = (s?Wx:Wa)[e]
__global__ __launch_bounds__(256) void cvt_w_kernel(const float* __restrict__ Wa,
                                                    const float* __restrict__ Wx,
                                                    uint16_t* __restrict__ wc){
  int i = blockIdx.x * 256 + threadIdx.x;   // float4 units
  const int c    = i >> 8;
  const int col4 = i & 255;
  const int e = ((c >> 5) << 4) | (c & 15);
  const int s = (c >> 4) & 1;
  const float* src = (s ? Wx : Wa) + (size_t)e*DD + col4*4;
  float4 f = *(const float4*)src;
  ushort4 o;
  o.x = f2bf(f.x); o.y = f2bf(f.y); o.z = f2bf(f.z); o.w = f2bf(f.w);
  ((ushort4*)wc)[i] = o;
}

// ---------------- dual GEMM, 256x256 tile, BK=32, 3-buffer pipeline ----------------
// C[m][c] = sum_d x[m][d]*wc[c][d]; col pairs (even n -> a, odd n -> v);
// av[t*SS+b*DD+e]: low16 = a, high16 = tanh(v + bv)
__global__ __launch_bounds__(512, 2) void gemm_dual(const uint16_t* __restrict__ xb,
                                                    const uint16_t* __restrict__ wc,
                                                    const float* __restrict__ bv,
                                                    uint32_t* __restrict__ av){
  // 96 KiB: buffer r (r=0,1,2) at byte r*32768: A[256][32] then B[256][32] (+16384)
  __shared__ __align__(16) uint16_t lds[49152];
  char* ldsc = (char*)lds;

  const int tid  = threadIdx.x;        // 0..511
  const int lane = tid & 63;
  const int w    = tid >> 6;           // wave 0..7
  const int wm   = w >> 2;             // 0..1  (M half)
  const int wn   = w & 3;              // 0..3  (N quarter)
  const int fr   = lane & 15;
  const int fq   = lane >> 4;

  // XCD-aware bijective swizzle: 1024 blocks, 8 XCDs
  const int bid = blockIdx.x;
  const int bsw = (bid & 7) * 128 + (bid >> 3);
  const int bm  = (bsw >> 3) << 8;     // row-tile * 256
  const int bn  = (bsw & 7) << 8;      // col-tile * 256

  f32x4 acc[8][4] = {};

  // staging: thread -> row tid>>2 (0..127), phys 16B slot tid&3; source pre-swizzled
  const int srow = tid >> 2;
  const int soff = ((tid & 3) ^ ((tid >> 3) & 3)) * 8;   // element offset in 32-elem row

  // unit u of K-tile kt into buffer byte-offset bufb:
  //  u=0: A rows 0-127, u=1: A rows 128-255, u=2: B rows 0-127, u=3: B rows 128-255
  #define STAGE_UNIT(kt, bufb, u) { \
    const uint16_t* s_ = ((u) < 2) ? xb : wc; \
    const int gb_ = ((u) < 2) ? bm : bn; \
    const int reg_ = ((u) < 2) ? 0 : 16384; \
    const int rb_ = ((u) & 1) * 128; \
    const uint16_t* g_ = s_ + (size_t)(gb_ + rb_ + srow)*KDIM + (kt)*32 + soff; \
    char* d_ = ldsc + (bufb) + reg_ + rb_*64 + w*1024; \
    __builtin_amdgcn_global_load_lds((const __attribute__((address_space(1))) void*)g_, \
                                     (__attribute__((address_space(3))) void*)d_, 16, 0, 0); \
  }

  // lane-constant fragment offsets (swizzled): slot = fq ^ ((fr>>1)&3)
  const int slotoff = (fq ^ ((fr >> 1) & 3)) * 16;
  const int aoff0 = (wm*128 + fr)*64 + slotoff;            // + m*1024 (+4096 for m>=4)
  const int boff0 = 16384 + (wn*64 + fr)*64 + slotoff;     // + n*1024

  // prologue: stage tiles 0 and 1
  STAGE_UNIT(0, 0, 0) STAGE_UNIT(0, 0, 1) STAGE_UNIT(0, 0, 2) STAGE_UNIT(0, 0, 3)
  STAGE_UNIT(1, 32768, 0) STAGE_UNIT(1, 32768, 1) STAGE_UNIT(1, 32768, 2) STAGE_UNIT(1, 32768, 3)
  asm volatile("s_waitcnt vmcnt(4)" ::: "memory");   // tile 0 landed; tile 1 in flight
  __builtin_amdgcn_s_barrier();

  int bR = 0;
  for (int t = 0; t < 32; ++t){
    const int bRb = bR * 32768;
    const int bW  = (bR == 0) ? 2 : (bR - 1);   // == (t+2)%3
    const int bWb = bW * 32768;

    short8 aF[4], bF[4];
    // ---- phase 0: rows wm*128+0..63, all 64 cols ----
    #pragma unroll
    for (int m = 0; m < 4; ++m)
      aF[m] = *(const short8*)(ldsc + bRb + aoff0 + m*1024);
    #pragma unroll
    for (int n = 0; n < 4; ++n)
      bF[n] = *(const short8*)(ldsc + bRb + boff0 + n*1024);
    if (t < 30){ STAGE_UNIT(t+2, bWb, 0) STAGE_UNIT(t+2, bWb, 1) }
    __builtin_amdgcn_s_barrier();
    asm volatile("s_waitcnt lgkmcnt(0)" ::: "memory");
    __builtin_amdgcn_sched_barrier(0);
    __builtin_amdgcn_s_setprio(1);
    #pragma unroll
    for (int m = 0; m < 4; ++m)
      #pragma unroll
      for (int n = 0; n < 4; ++n)
        acc[m][n] = __builtin_amdgcn_mfma_f32_16x16x32_bf16(aF[m], bF[n], acc[m][n], 0, 0, 0);
    __builtin_amdgcn_s_setprio(0);
    __builtin_amdgcn_s_barrier();

    // ---- phase 1: rows wm*128+64..127, bF register-carried ----
    #pragma unroll
    for (int m = 0; m < 4; ++m)
      aF[m] = *(const short8*)(ldsc + bRb + aoff0 + 4096 + m*1024);
    if (t < 30){ STAGE_UNIT(t+2, bWb, 2) STAGE_UNIT(t+2, bWb, 3) }
    __builtin_amdgcn_s_barrier();
    asm volatile("s_waitcnt lgkmcnt(0)" ::: "memory");
    __builtin_amdgcn_sched_barrier(0);
    __builtin_amdgcn_s_setprio(1);
    #pragma unroll
    for (int m = 0; m < 4; ++m)
      #pragma unroll
      for (int n = 0; n < 4; ++n)
        acc[4+m][n] = __builtin_amdgcn_mfma_f32_16x16x32_bf16(aF[m], bF[n], acc[4+m][n], 0, 0, 0);
    __builtin_amdgcn_s_setprio(0);
    if (t < 30){
      asm volatile("s_waitcnt vmcnt(4)" ::: "memory");   // tile t+1 landed; t+2 in flight
    } else if (t == 30){
      asm volatile("s_waitcnt vmcnt(0)" ::: "memory");   // tile 31 landed
    }
    __builtin_amdgcn_s_barrier();

    bR = (bR == 2) ? 0 : (bR + 1);
  }
  #undef STAGE_UNIT

  // epilogue: C/D col=lane&15, row=(lane>>4)*4+j; frag pair (2p,2p+1) = (a,v).
  // p innermost so both halves of each 128B av line are written back-to-back.
  const int ebase = (bn + wn*64) >> 1;
  const float bvn0 = bv[ebase + fr];
  const float bvn1 = bv[ebase + 16 + fr];
  #pragma unroll
  for (int m = 0; m < 8; ++m){
    #pragma unroll
    for (int j = 0; j < 4; ++j){
      const int row = bm + wm*128 + m*16 + fq*4 + j;
      const int tt = row >> 5, b = row & 31;
      const size_t base = (size_t)tt*SS + (size_t)b*DD;
      const float a0  = acc[m][0][j];
      const float vt0 = tanh_fast(acc[m][1][j] + bvn0);
      av[base + ebase + fr] = (uint32_t)f2bf(a0) | ((uint32_t)f2bf(vt0) << 16);
      const float a1  = acc[m][2][j];
      const float vt1 = tanh_fast(acc[m][3][j] + bvn1);
      av[base + ebase + 16 + fr] = (uint32_t)f2bf(a1) | ((uint32_t)f2bf(vt1) << 16);
    }
  }
}

// ---------------- scan over t: one thread per (b,e), depth-32 prefetch ----------------
#define SCAN_STEP(u, tcur)                                        \
  {                                                               \
    const float a_ = bf2f((uint16_t)(u));                         \
    const float v_ = bf2f((uint16_t)((u) >> 16));                 \
    const float al_ = sigmoid_fast(a_ + da*h + ba);               \
    h = al_*(h - v_) + v_;                                        \
    const float sg_ = sigmoid_fast(h);                            \
    __builtin_nontemporal_store(h*h*sg_, &outs[(size_t)(tcur)*SS + idx]); \
    __builtin_nontemporal_store(h, &houts[(size_t)((tcur)+1)*SS + idx]);  \
  }

__global__ __launch_bounds__(64) void scan_kernel(const uint32_t* __restrict__ av,
                                                  const float* __restrict__ h0,
                                                  const float* __restrict__ d_alpha,
                                                  const float* __restrict__ b_alpha,
                                                  float* __restrict__ outs,
                                                  float* __restrict__ houts){
  const int idx = blockIdx.x * 64 + threadIdx.x;   // 0..32767 = b*D+e
  const int e = idx & (DD-1);
  const float da = d_alpha[e];
  const float ba = b_alpha[e];
  float h = h0[idx];
  __builtin_nontemporal_store(h, &houts[idx]);

  uint32_t bufA[32], bufB[32];
  #pragma unroll
  for (int j = 0; j < 32; ++j) bufA[j] = av[(size_t)j*SS + idx];

  for (int t0 = 0; t0 < TT; t0 += 64){
    #pragma unroll
    for (int j = 0; j < 32; ++j) bufB[j] = av[(size_t)(t0+32+j)*SS + idx];
    #pragma unroll
    for (int j = 0; j < 32; ++j) SCAN_STEP(bufA[j], t0 + j);
    if (t0 + 64 < TT){
      #pragma unroll
      for (int j = 0; j < 32; ++j) bufA[j] = av[(size_t)(t0+64+j)*SS + idx];
    }
    #pragma unroll
    for (int j = 0; j < 32; ++j) SCAN_STEP(bufB[j], t0 + 32 + j);
  }
}

extern "C" void kernel_launch(void* const* d_in, const int* in_sizes, int n_in,
                              void* d_out, int out_size, void* d_ws, size_t ws_size,
                              hipStream_t stream){
  const float* x  = (const float*)d_in[0];
  const float* h0 = (const float*)d_in[1];
  const float* Wa = (const float*)d_in[2];
  const float* da = (const float*)d_in[3];
  const float* ba = (const float*)d_in[4];
  const float* Wx = (const float*)d_in[5];
  const float* bv = (const float*)d_in[6];

  float* outs  = (float*)d_out;                       // [T,B,D]
  float* houts = outs + (size_t)TT*BB*DD;             // [T+1,B,D]

  // workspace: wc 4MB | xb 64MB | av 128MB
  uint8_t* ws = (uint8_t*)d_ws;
  uint16_t* wcb = (uint16_t*)ws;
  uint16_t* xb  = (uint16_t*)(ws + (size_t)NCOLS*KDIM*2);
  uint32_t* av  = (uint32_t*)(ws + (size_t)NCOLS*KDIM*2 + (size_t)MROWS*KDIM*2);

  hipLaunchKernelGGL(cvt_w_kernel, dim3(2048), dim3(256), 0, stream, Wa, Wx, wcb);
  hipLaunchKernelGGL(cvt_x_kernel, dim3(2048), dim3(256), 0, stream, x, xb, MROWS*KDIM/4);
  hipLaunchKernelGGL(gemm_dual, dim3((NCOLS/256)*(MROWS/256)), dim3(512), 0, stream,
                     xb, wcb, bv, av);
  hipLaunchKernelGGL(scan_kernel, dim3(SS/64), dim3(64), 0, stream,
                     av, h0, da, ba, outs, houts);
}

// Round 6
// 254.441 us; speedup vs baseline: 2.4275x; 1.0467x over previous
//
#include <hip/hip_runtime.h>
#include <hip/hip_bf16.h>
#include <stdint.h>

#define TT 1024
#define BB 32
#define DD 1024
#define MROWS (TT*BB)   // 32768
#define NCOLS (2*DD)    // 2048
#define KDIM  (DD)      // 1024
#define SS (BB*DD)      // 32768

typedef __attribute__((ext_vector_type(8))) short short8;
typedef __attribute__((ext_vector_type(4))) float f32x4;

__device__ __forceinline__ float bf2f(uint16_t u){
  union { uint32_t u; float f; } c; c.u = ((uint32_t)u) << 16; return c.f;
}
__device__ __forceinline__ uint16_t f2bf(float f){
  union { float f; uint32_t u; } c; c.f = f;
  uint32_t u = c.u;
  u += 0x7FFFu + ((u >> 16) & 1u);   // RNE
  return (uint16_t)(u >> 16);
}
__device__ __forceinline__ float tanh_fast(float x){
  return 1.f - 2.f/(1.f + __expf(2.f*x));
}
__device__ __forceinline__ float sigmoid_fast(float x){
  return __builtin_amdgcn_rcpf(1.f + __expf(-x));
}

// ---------------- convert x to bf16 ----------------
__global__ __launch_bounds__(256) void cvt_x_kernel(const float* __restrict__ x,
                                                    uint16_t* __restrict__ xb, int n4){
  int i = blockIdx.x * 256 + threadIdx.x;
  int stride = gridDim.x * 256;
  for (; i < n4; i += stride){
    float4 f = ((const float4*)x)[i];
    ushort4 o;
    o.x = f2bf(f.x); o.y = f2bf(f.y); o.z = f2bf(f.z); o.w = f2bf(f.w);
    ((ushort4*)xb)[i] = o;
  }
}

// ---------------- pack W to bf16, pair-interleaved ----------------
// wc row c: e = ((c>>5)<<4)|(c&15), s=(c>>4)&1; wc[c] = (s?Wx:Wa)[e]
__global__ __launch_bounds__(256) void cvt_w_kernel(const float* __restrict__ Wa,
                                                    const float* __restrict__ Wx,
                                                    uint16_t* __restrict__ wc){
  int i = blockIdx.x * 256 + threadIdx.x;   // float4 units
  const int c    = i >> 8;
  const int col4 = i & 255;
  const int e = ((c >> 5) << 4) | (c & 15);
  const int s = (c >> 4) & 1;
  const float* src = (s ? Wx : Wa) + (size_t)e*DD + col4*4;
  float4 f = *(const float4*)src;
  ushort4 o;
  o.x = f2bf(f.x); o.y = f2bf(f.y); o.z = f2bf(f.z); o.w = f2bf(f.w);
  ((ushort4*)wc)[i] = o;
}

// ---------------- dual GEMM, 256x256 tile, BK=32, 3-buffer, 1 barrier/tile ----------------
// C[m][c] = sum_d x[m][d]*wc[c][d]; col pairs (even n -> a, odd n -> v);
// av[t*SS+b*DD+e]: low16 = a, high16 = tanh(v + bv)
__global__ __launch_bounds__(512, 2) void gemm_dual(const uint16_t* __restrict__ xb,
                                                    const uint16_t* __restrict__ wc,
                                                    const float* __restrict__ bv,
                                                    uint32_t* __restrict__ av){
  // 96 KiB: buffer r (r=0,1,2) at byte r*32768: A[256][32] then B[256][32] (+16384)
  __shared__ __align__(16) uint16_t lds[49152];
  char* ldsc = (char*)lds;

  const int tid  = threadIdx.x;        // 0..511
  const int lane = tid & 63;
  const int w    = tid >> 6;           // wave 0..7
  const int wm   = w >> 2;             // 0..1  (M half)
  const int wn   = w & 3;              // 0..3  (N quarter)
  const int fr   = lane & 15;
  const int fq   = lane >> 4;

  // XCD-aware bijective swizzle: 1024 blocks, 8 XCDs
  const int bid = blockIdx.x;
  const int bsw = (bid & 7) * 128 + (bid >> 3);
  const int bm  = (bsw >> 3) << 8;     // row-tile * 256
  const int bn  = (bsw & 7) << 8;      // col-tile * 256

  f32x4 acc[8][4] = {};

  // staging: thread -> row tid>>2 (0..127), phys 16B slot tid&3; source pre-swizzled
  const int srow = tid >> 2;
  const int soff = ((tid & 3) ^ ((tid >> 3) & 3)) * 8;   // element offset in 32-elem row

  // unit u of K-tile kt into buffer byte-offset bufb:
  //  u=0: A rows 0-127, u=1: A rows 128-255, u=2: B rows 0-127, u=3: B rows 128-255
  #define STAGE_UNIT(kt, bufb, u) { \
    const uint16_t* s_ = ((u) < 2) ? xb : wc; \
    const int gb_ = ((u) < 2) ? bm : bn; \
    const int reg_ = ((u) < 2) ? 0 : 16384; \
    const int rb_ = ((u) & 1) * 128; \
    const uint16_t* g_ = s_ + (size_t)(gb_ + rb_ + srow)*KDIM + (kt)*32 + soff; \
    char* d_ = ldsc + (bufb) + reg_ + rb_*64 + w*1024; \
    __builtin_amdgcn_global_load_lds((const __attribute__((address_space(1))) void*)g_, \
                                     (__attribute__((address_space(3))) void*)d_, 16, 0, 0); \
  }

  // lane-constant fragment offsets (swizzled): slot = fq ^ ((fr>>1)&3)
  const int slotoff = (fq ^ ((fr >> 1) & 3)) * 16;
  const int aoff0 = (wm*128 + fr)*64 + slotoff;            // + m*1024 (+4096 for m>=4)
  const int boff0 = 16384 + (wn*64 + fr)*64 + slotoff;     // + n*1024

  // prologue: stage tiles 0 and 1
  STAGE_UNIT(0, 0, 0) STAGE_UNIT(0, 0, 1) STAGE_UNIT(0, 0, 2) STAGE_UNIT(0, 0, 3)
  STAGE_UNIT(1, 32768, 0) STAGE_UNIT(1, 32768, 1) STAGE_UNIT(1, 32768, 2) STAGE_UNIT(1, 32768, 3)
  asm volatile("s_waitcnt vmcnt(4)" ::: "memory");   // tile 0 landed; tile 1 in flight
  __builtin_amdgcn_s_barrier();

  int bR = 0;
  for (int t = 0; t < 32; ++t){
    const int bRb = bR * 32768;
    const int bW  = (bR == 0) ? 2 : (bR - 1);   // == (t+2)%3
    const int bWb = bW * 32768;

    // Tile body: no internal barriers. Compiler inserts fine-grained lgkmcnt
    // between ds_read and dependent MFMA; waves de-phase within the tile so
    // one wave's MFMA overlaps another's ds_read on the CU.
    short8 aF[4], bF[4], aG[4];
    #pragma unroll
    for (int m = 0; m < 4; ++m)
      aF[m] = *(const short8*)(ldsc + bRb + aoff0 + m*1024);
    #pragma unroll
    for (int n = 0; n < 4; ++n)
      bF[n] = *(const short8*)(ldsc + bRb + boff0 + n*1024);
    if (t < 30){ STAGE_UNIT(t+2, bWb, 0) STAGE_UNIT(t+2, bWb, 1) }

    #pragma unroll
    for (int m = 0; m < 4; ++m)
      #pragma unroll
      for (int n = 0; n < 4; ++n)
        acc[m][n] = __builtin_amdgcn_mfma_f32_16x16x32_bf16(aF[m], bF[n], acc[m][n], 0, 0, 0);

    #pragma unroll
    for (int m = 0; m < 4; ++m)
      aG[m] = *(const short8*)(ldsc + bRb + aoff0 + 4096 + m*1024);
    if (t < 30){ STAGE_UNIT(t+2, bWb, 2) STAGE_UNIT(t+2, bWb, 3) }

    #pragma unroll
    for (int m = 0; m < 4; ++m)
      #pragma unroll
      for (int n = 0; n < 4; ++n)
        acc[4+m][n] = __builtin_amdgcn_mfma_f32_16x16x32_bf16(aG[m], bF[n], acc[4+m][n], 0, 0, 0);

    // tile boundary: ensure tile t+1 landed (counted wait, never 0 mid-loop),
    // then one barrier. The asm memory clobber also fences ds_read motion.
    if (t < 30){
      asm volatile("s_waitcnt vmcnt(4)" ::: "memory");
      __builtin_amdgcn_s_barrier();
    } else if (t == 30){
      asm volatile("s_waitcnt vmcnt(0)" ::: "memory");
      __builtin_amdgcn_s_barrier();
    }

    bR = (bR == 2) ? 0 : (bR + 1);
  }
  #undef STAGE_UNIT

  // epilogue: C/D col=lane&15, row=(lane>>4)*4+j; frag pair (2p,2p+1) = (a,v).
  // p innermost so both halves of each 128B av line are written back-to-back.
  const int ebase = (bn + wn*64) >> 1;
  const float bvn0 = bv[ebase + fr];
  const float bvn1 = bv[ebase + 16 + fr];
  #pragma unroll
  for (int m = 0; m < 8; ++m){
    #pragma unroll
    for (int j = 0; j < 4; ++j){
      const int row = bm + wm*128 + m*16 + fq*4 + j;
      const int tt = row >> 5, b = row & 31;
      const size_t base = (size_t)tt*SS + (size_t)b*DD;
      const float a0  = acc[m][0][j];
      const float vt0 = tanh_fast(acc[m][1][j] + bvn0);
      av[base + ebase + fr] = (uint32_t)f2bf(a0) | ((uint32_t)f2bf(vt0) << 16);
      const float a1  = acc[m][2][j];
      const float vt1 = tanh_fast(acc[m][3][j] + bvn1);
      av[base + ebase + 16 + fr] = (uint32_t)f2bf(a1) | ((uint32_t)f2bf(vt1) << 16);
    }
  }
}

// ---------------- scan over t: one thread per (b,e), depth-32 prefetch ----------------
#define SCAN_STEP(u, tcur)                                        \
  {                                                               \
    const float a_ = bf2f((uint16_t)(u));                         \
    const float v_ = bf2f((uint16_t)((u) >> 16));                 \
    const float al_ = sigmoid_fast(a_ + da*h + ba);               \
    h = al_*(h - v_) + v_;                                        \
    const float sg_ = sigmoid_fast(h);                            \
    __builtin_nontemporal_store(h*h*sg_, &outs[(size_t)(tcur)*SS + idx]); \
    __builtin_nontemporal_store(h, &houts[(size_t)((tcur)+1)*SS + idx]);  \
  }

__global__ __launch_bounds__(64) void scan_kernel(const uint32_t* __restrict__ av,
                                                  const float* __restrict__ h0,
                                                  const float* __restrict__ d_alpha,
                                                  const float* __restrict__ b_alpha,
                                                  float* __restrict__ outs,
                                                  float* __restrict__ houts){
  const int idx = blockIdx.x * 64 + threadIdx.x;   // 0..32767 = b*D+e
  const int e = idx & (DD-1);
  const float da = d_alpha[e];
  const float ba = b_alpha[e];
  float h = h0[idx];
  __builtin_nontemporal_store(h, &houts[idx]);

  uint32_t bufA[32], bufB[32];
  #pragma unroll
  for (int j = 0; j < 32; ++j) bufA[j] = av[(size_t)j*SS + idx];

  for (int t0 = 0; t0 < TT; t0 += 64){
    #pragma unroll
    for (int j = 0; j < 32; ++j) bufB[j] = av[(size_t)(t0+32+j)*SS + idx];
    #pragma unroll
    for (int j = 0; j < 32; ++j) SCAN_STEP(bufA[j], t0 + j);
    if (t0 + 64 < TT){
      #pragma unroll
      for (int j = 0; j < 32; ++j) bufA[j] = av[(size_t)(t0+64+j)*SS + idx];
    }
    #pragma unroll
    for (int j = 0; j < 32; ++j) SCAN_STEP(bufB[j], t0 + 32 + j);
  }
}

extern "C" void kernel_launch(void* const* d_in, const int* in_sizes, int n_in,
                              void* d_out, int out_size, void* d_ws, size_t ws_size,
                              hipStream_t stream){
  const float* x  = (const float*)d_in[0];
  const float* h0 = (const float*)d_in[1];
  const float* Wa = (const float*)d_in[2];
  const float* da = (const float*)d_in[3];
  const float* ba = (const float*)d_in[4];
  const float* Wx = (const float*)d_in[5];
  const float* bv = (const float*)d_in[6];

  float* outs  = (float*)d_out;                       // [T,B,D]
  float* houts = outs + (size_t)TT*BB*DD;             // [T+1,B,D]

  // workspace: wc 4MB | xb 64MB | av 128MB
  uint8_t* ws = (uint8_t*)d_ws;
  uint16_t* wcb = (uint16_t*)ws;
  uint16_t* xb  = (uint16_t*)(ws + (size_t)NCOLS*KDIM*2);
  uint32_t* av  = (uint32_t*)(ws + (size_t)NCOLS*KDIM*2 + (size_t)MROWS*KDIM*2);

  hipLaunchKernelGGL(cvt_w_kernel, dim3(2048), dim3(256), 0, stream, Wa, Wx, wcb);
  hipLaunchKernelGGL(cvt_x_kernel, dim3(2048), dim3(256), 0, stream, x, xb, MROWS*KDIM/4);
  hipLaunchKernelGGL(gemm_dual, dim3((NCOLS/256)*(MROWS/256)), dim3(512), 0, stream,
                     xb, wcb, bv, av);
  hipLaunchKernelGGL(scan_kernel, dim3(SS/64), dim3(64), 0, stream,
                     av, h0, da, ba, outs, houts);
}